// Round 9
// baseline (280.899 us; speedup 1.0000x reference)
//
#include <hip/hip_runtime.h>
#include <stdint.h>

#define DIN   4096
#define DOUT  4096
#define MTOT  8192
#define NT    64                      /* K-tiles of BK=64 */

#define BM    256
#define BN    256
#define GRID_M (MTOT / BM)            /* 32 */
#define GRID_N (DOUT / BN)            /* 16 */
#define NWG   (GRID_M * GRID_N)       /* 512 */

typedef __attribute__((ext_vector_type(4))) float        f32x4;
typedef __attribute__((ext_vector_type(4))) int          i32x4;
typedef __attribute__((ext_vector_type(4))) unsigned int u32x4;
typedef __attribute__((ext_vector_type(2))) unsigned int u32x2;
typedef __attribute__((ext_vector_type(8))) short        bf16x8;

__device__ __forceinline__ unsigned int pack_bf2_rne(float a, float b) {
  unsigned int ua = __builtin_bit_cast(unsigned int, a);
  unsigned int ub = __builtin_bit_cast(unsigned int, b);
  ua += 0x7fffu + ((ua >> 16) & 1u);
  ub += 0x7fffu + ((ub >> 16) & 1u);
  return (ua >> 16) | (ub & 0xffff0000u);
}

// (w - off) integer, |v| <= 135 < 256 -> exact in bf16.
__device__ __forceinline__ unsigned int pack_bf2_exact(int a, int b) {
  unsigned int ua = __builtin_bit_cast(unsigned int, (float)a);
  unsigned int ub = __builtin_bit_cast(unsigned int, (float)b);
  return (ua >> 16) | (ub & 0xffff0000u);
}

// ---- merged pre-pass: x (fp32)->bf16 and (w-off)->bf16, 16KiB units of
// [128 rows][64 k], pre-swizzled: byte layout row*128 + ((chunk*16)^((row&7)<<4))
#define TOTA (MTOT * (DIN / 8))
#define TOTB (DOUT * (DIN / 8))
__global__ __launch_bounds__(256) void conv_kernel(const float* __restrict__ X,
                                                   u32x4* __restrict__ wsA,
                                                   const int* __restrict__ W,
                                                   const int* __restrict__ Off,
                                                   u32x4* __restrict__ wsB) {
  for (int idx = blockIdx.x * 256 + threadIdx.x; idx < TOTA + TOTB;
       idx += gridDim.x * 256) {
    if (idx < TOTA) {
      const int m  = idx >> 9;
      const int c  = idx & 511;
      const int kt = c >> 3, ch = c & 7;
      const int rb = m >> 7, row = m & 127;
      const f32x4* src = (const f32x4*)(X + ((long)m << 12) + kt * 64 + ch * 8);
      f32x4 f0 = src[0], f1 = src[1];
      u32x4 d;
      d[0] = pack_bf2_rne(f0[0], f0[1]);
      d[1] = pack_bf2_rne(f0[2], f0[3]);
      d[2] = pack_bf2_rne(f1[0], f1[1]);
      d[3] = pack_bf2_rne(f1[2], f1[3]);
      wsA[(long)(rb * NT + kt) * 1024 + row * 8 + (ch ^ (row & 7))] = d;
    } else {
      const int j  = idx - TOTA;
      const int n  = j >> 9;
      const int c  = j & 511;
      const int kt = c >> 3, ch = c & 7;
      const int nb = n >> 7, row = n & 127;
      const i32x4* src = (const i32x4*)(W + ((long)n << 12) + kt * 64 + ch * 8);
      const int off = Off[n];
      i32x4 w0 = src[0], w1 = src[1];
      u32x4 d;
      d[0] = pack_bf2_exact(w0[0] - off, w0[1] - off);
      d[1] = pack_bf2_exact(w0[2] - off, w0[3] - off);
      d[2] = pack_bf2_exact(w1[0] - off, w1[1] - off);
      d[3] = pack_bf2_exact(w1[2] - off, w1[3] - off);
      wsB[(long)(nb * NT + kt) * 1024 + row * 8 + (ch ^ (row & 7))] = d;
    }
  }
}

// ========== 1-barrier-per-tile 256x256 GEMM (asm-scheduled, free wave drift) ==========
// Per tile t (buf = t&1):
//   STAGE A(t+1),B(t+1) -> buf^1 (8 global_load_lds, issued FIRST)
//   12 ds_reads (k0) ; k0 MFMA cascade m0..m3
//   12 ds_reads (k1, hoisted) ; k0 cascade m4..m7 gated LGKM(15..12)
//   k1 cascade m0..m7 gated LGKM(7..0)
//   WAITV(0) ; BAR
// Invariants: (a) every wave's WAITV(0) [retires its stage(t+1)] precedes the
// single BAR -> all staging retired+barrier-crossed before any t+1 read.
// (b) each wave's tile-t reads complete at its lgkm gates before it reaches BAR
// -> staging t+2 into t's buffer (after next BAR) is WAR-safe.
// DS returns are in-order per wave, so after issuing 12 k1 reads, LGKM(12+r)
// bounds k0-remaining by r. Max lgkmcnt 15 respected. WAITV(0) costs ~0: the 8
// loads were issued ~4000 cyc earlier (>> 900-cyc HBM latency).

#define BAR()   __builtin_amdgcn_s_barrier()
#define SB()    __builtin_amdgcn_sched_barrier(0)
#define LGKM_(N) asm volatile("s_waitcnt lgkmcnt(" #N ")" ::: "memory")
#define LGKM(N)  LGKM_(N)
#define WAITV(N) asm volatile("s_waitcnt vmcnt(" #N ")" ::: "memory")

typedef __attribute__((address_space(3))) const char* ldsp;

#define DSR(dst, p, IMM) \
  asm volatile("ds_read_b128 %0, %1 offset:" #IMM : "=v"(dst) : "v"(p))

#define STAGE(ldsArr, bufc, h, basePtr, t)                                      \
  { const u32x4* s_ = (basePtr) + (long)(t) * 1024;                             \
    _Pragma("unroll")                                                           \
    for (int i_ = 0; i_ < 2; ++i_) {                                            \
      const int o_ = tid + i_ * 512;                                            \
      __builtin_amdgcn_global_load_lds(                                         \
          (const __attribute__((address_space(1))) void*)(s_ + o_),             \
          (__attribute__((address_space(3))) void*)(&ldsArr[bufc][h][0][0] + o_),\
          16, 0, 0);                                                            \
    } }

#define RDB4(bS_, pB_)                                                          \
  DSR(bS_[0], pB_, 0);    DSR(bS_[1], pB_, 2048);                               \
  DSR(bS_[2], pB_, 4096); DSR(bS_[3], pB_, 6144);
#define RDA8(aS_, pA_)                                                          \
  DSR(aS_[0], pA_, 0);     DSR(aS_[1], pA_, 2048);                              \
  DSR(aS_[2], pA_, 4096);  DSR(aS_[3], pA_, 6144);                              \
  DSR(aS_[4], pA_, 8192);  DSR(aS_[5], pA_, 10240);                             \
  DSR(aS_[6], pA_, 12288); DSR(aS_[7], pA_, 14336);

#define MMA4(aS_, bS_, m)                                                       \
  { _Pragma("unroll") for (int n_ = 0; n_ < 4; ++n_)                            \
      acc[m][n_] = __builtin_amdgcn_mfma_f32_16x16x32_bf16(                     \
          aS_[m], bS_[n_], acc[m][n_], 0, 0, 0); }

#define TILE(pAc0, pAc1, pBc0, pBc1, NB, t, SG, WV)                             \
  if (SG) { STAGE(ldsA, NB, 0, bA0, (t) + 1) STAGE(ldsA, NB, 1, bA1, (t) + 1)  \
            STAGE(ldsB, NB, 0, bB0, (t) + 1) STAGE(ldsB, NB, 1, bB1, (t) + 1) }\
  RDB4(bP, pBc0) RDA8(aP, pAc0)                                                 \
  __builtin_amdgcn_s_setprio(1);                                                \
  LGKM(7); SB(); MMA4(aP, bP, 0)                                                \
  LGKM(6); SB(); MMA4(aP, bP, 1)                                                \
  LGKM(5); SB(); MMA4(aP, bP, 2)                                                \
  LGKM(4); SB(); MMA4(aP, bP, 3)                                                \
  __builtin_amdgcn_s_setprio(0);                                                \
  RDB4(bQ, pBc1) RDA8(aQ, pAc1)                                                 \
  __builtin_amdgcn_s_setprio(1);                                                \
  LGKM(15); SB(); MMA4(aP, bP, 4)                                               \
  LGKM(14); SB(); MMA4(aP, bP, 5)                                               \
  LGKM(13); SB(); MMA4(aP, bP, 6)                                               \
  LGKM(12); SB(); MMA4(aP, bP, 7)                                               \
  LGKM(7);  SB(); MMA4(aQ, bQ, 0)                                               \
  LGKM(6);  SB(); MMA4(aQ, bQ, 1)                                               \
  LGKM(5);  SB(); MMA4(aQ, bQ, 2)                                               \
  LGKM(4);  SB(); MMA4(aQ, bQ, 3)                                               \
  LGKM(3);  SB(); MMA4(aQ, bQ, 4)                                               \
  LGKM(2);  SB(); MMA4(aQ, bQ, 5)                                               \
  LGKM(1);  SB(); MMA4(aQ, bQ, 6)                                               \
  LGKM(0);  SB(); MMA4(aQ, bQ, 7)                                               \
  __builtin_amdgcn_s_setprio(0);                                                \
  WV; BAR();

__global__ __launch_bounds__(512, 2) void gemm8_kernel(
    const u32x4* __restrict__ wsA, const u32x4* __restrict__ wsB,
    const float* __restrict__ Scale, float* __restrict__ Out) {
  __shared__ u32x4 ldsA[2][2][128][8];   // [buf][half][row][chunk16] = 64 KiB
  __shared__ u32x4 ldsB[2][2][128][8];

  const int tid  = threadIdx.x;
  const int lane = tid & 63;
  const int wid  = tid >> 6;
  const int wr   = wid >> 2;     // A half
  const int wc   = wid & 3;      // 64-col N slice
  const int wch  = wc >> 1;      // B half
  const int wcl  = wc & 1;

  int gid = (int)blockIdx.x;
  gid = (gid & 7) * (NWG >> 3) + (gid >> 3);   // bijective XCD swizzle (512%8==0)
  const int wg_m = gid / GRID_N;
  const int wg_n = gid % GRID_N;

  const int riA = lane & 15;
  const int c0  = lane >> 4;
  const int cs0 = c0 ^ (riA & 7);              // logical chunk c0   ^ row-swz
  const int cs1 = (4 + c0) ^ (riA & 7);        // logical chunk 4+c0 ^ row-swz

  // per-wave LDS read base pointers (AS3); row strides are literal offsets
  ldsp pA0c0 = (ldsp)&ldsA[0][wr][riA][cs0];
  ldsp pA0c1 = (ldsp)&ldsA[0][wr][riA][cs1];
  ldsp pA1c0 = (ldsp)&ldsA[1][wr][riA][cs0];
  ldsp pA1c1 = (ldsp)&ldsA[1][wr][riA][cs1];
  ldsp pB0c0 = (ldsp)&ldsB[0][wch][wcl * 64 + riA][cs0];
  ldsp pB0c1 = (ldsp)&ldsB[0][wch][wcl * 64 + riA][cs1];
  ldsp pB1c0 = (ldsp)&ldsB[1][wch][wcl * 64 + riA][cs0];
  ldsp pB1c1 = (ldsp)&ldsB[1][wch][wcl * 64 + riA][cs1];

  const u32x4* bA0 = wsA + (long)(wg_m * 2 + 0) * NT * 1024;
  const u32x4* bA1 = wsA + (long)(wg_m * 2 + 1) * NT * 1024;
  const u32x4* bB0 = wsB + (long)(wg_n * 2 + 0) * NT * 1024;
  const u32x4* bB1 = wsB + (long)(wg_n * 2 + 1) * NT * 1024;

  f32x4 acc[8][4];
#pragma unroll
  for (int m = 0; m < 8; ++m)
#pragma unroll
    for (int n = 0; n < 4; ++n) acc[m][n] = (f32x4){0.f, 0.f, 0.f, 0.f};

  bf16x8 aP[8], aQ[8], bP[4], bQ[4];

  // prologue: stage tile 0 into buf0; retire; barrier
  STAGE(ldsA, 0, 0, bA0, 0) STAGE(ldsA, 0, 1, bA1, 0)
  STAGE(ldsB, 0, 0, bB0, 0) STAGE(ldsB, 0, 1, bB1, 0)
  WAITV(0); BAR();

#pragma unroll 1
  for (int it = 0; it < 31; ++it) {            // tiles 0..61
    const int t = 2 * it;
    TILE(pA0c0, pA0c1, pB0c0, pB0c1, 1, t,     1, WAITV(0))
    TILE(pA1c0, pA1c1, pB1c0, pB1c1, 0, t + 1, 1, WAITV(0))
  }
  TILE(pA0c0, pA0c1, pB0c0, pB0c1, 1, 62, 1, WAITV(0))   // stages tile 63
  TILE(pA1c0, pA1c1, pB1c0, pB1c1, 0, 63, 0, (void)0)    // compute only

  // epilogue: out = acc * scale[col]; C/D map: col=lane&15, row=(lane>>4)*4+j
  const int col0 = wg_n * BN + wc * 64 + (lane & 15);
  const int row0 = wg_m * BM + wr * 128 + ((lane >> 4) << 2);
#pragma unroll
  for (int n = 0; n < 4; ++n) {
    const int col = col0 + n * 16;
    const float s = Scale[col];
#pragma unroll
    for (int m = 0; m < 8; ++m) {
      const int r = row0 + m * 16;
#pragma unroll
      for (int j = 0; j < 4; ++j)
        Out[(long)(r + j) * DOUT + col] = acc[m][n][j] * s;
    }
  }
}

// ================= fallback: fused 128x128 (round-1, proven) =================
__global__ __launch_bounds__(256, 2) void gemm_fused_kernel(
    const float* __restrict__ X, const int* __restrict__ W,
    const int* __restrict__ Off, const float* __restrict__ Scale,
    float* __restrict__ Out) {
  __shared__ char ldsA[2][128 * 64 * 2];
  __shared__ char ldsB[2][128 * 64 * 2];

  const int tid  = threadIdx.x;
  const int lane = tid & 63;
  const int wid  = tid >> 6;
  const int fwr  = wid >> 1;
  const int fwc  = wid & 1;

  int gid = (int)blockIdx.x;
  gid = (gid & 7) * (2048 >> 3) + (gid >> 3);
  const int wg_m = gid / 32;
  const int wg_n = gid % 32;
  const int brow = wg_m * 128;
  const int bcol = wg_n * 128;

  f32x4 acc[4][4];
#pragma unroll
  for (int m = 0; m < 4; ++m)
#pragma unroll
    for (int n = 0; n < 4; ++n) acc[m][n] = (f32x4){0.f, 0.f, 0.f, 0.f};

  int aoff[2][4], boff[2][4];
#pragma unroll
  for (int kk = 0; kk < 2; ++kk)
#pragma unroll
    for (int m = 0; m < 4; ++m) {
      const int kb = kk * 64 + ((lane >> 4) << 4);
      const int ra = fwr * 64 + m * 16 + (lane & 15);
      const int rb = fwc * 64 + m * 16 + (lane & 15);
      aoff[kk][m] = ra * 128 + (kb ^ ((ra & 7) << 4));
      boff[kk][m] = rb * 128 + (kb ^ ((rb & 7) << 4));
    }

  long xo[8], wo[8];
  int lo[8], ofv[8];
#pragma unroll
  for (int i = 0; i < 8; ++i) {
    const int idx = tid + i * 256;
    const int row = idx >> 4, c4 = idx & 15;
    xo[i] = (long)(brow + row) * DIN + c4 * 4;
    wo[i] = (long)(bcol + row) * DIN + c4 * 4;
    lo[i] = row * 128 + ((c4 * 8) ^ ((row & 7) << 4));
    ofv[i] = Off[bcol + row];
  }
  {
#pragma unroll
    for (int i = 0; i < 8; ++i) {
      f32x4 f = *(const f32x4*)(X + xo[i]);
      u32x2 d;
      d[0] = pack_bf2_rne(f[0], f[1]);
      d[1] = pack_bf2_rne(f[2], f[3]);
      *(u32x2*)(&ldsA[0][lo[i]]) = d;
    }
#pragma unroll
    for (int i = 0; i < 8; ++i) {
      i32x4 w = *(const i32x4*)(W + wo[i]);
      u32x2 d;
      d[0] = pack_bf2_exact(w[0] - ofv[i], w[1] - ofv[i]);
      d[1] = pack_bf2_exact(w[2] - ofv[i], w[3] - ofv[i]);
      *(u32x2*)(&ldsB[0][lo[i]]) = d;
    }
  }
  __syncthreads();
#pragma unroll 1
  for (int kt = 0; kt < NT; ++kt) {
    const int cur = kt & 1;
    const bool pf = (kt + 1 < NT);
    f32x4 fa[8];
    i32x4 fb[8];
    if (pf) {
      const int ko = (kt + 1) * 64;
#pragma unroll
      for (int i = 0; i < 8; ++i) fa[i] = *(const f32x4*)(X + xo[i] + ko);
#pragma unroll
      for (int i = 0; i < 8; ++i) fb[i] = *(const i32x4*)(W + wo[i] + ko);
    }
#pragma unroll
    for (int kk = 0; kk < 2; ++kk) {
      bf16x8 fa2[4], fb2[4];
#pragma unroll
      for (int m = 0; m < 4; ++m)
        fa2[m] = __builtin_bit_cast(bf16x8, *(const u32x4*)(&ldsA[cur][aoff[kk][m]]));
#pragma unroll
      for (int n = 0; n < 4; ++n)
        fb2[n] = __builtin_bit_cast(bf16x8, *(const u32x4*)(&ldsB[cur][boff[kk][n]]));
#pragma unroll
      for (int m = 0; m < 4; ++m)
#pragma unroll
        for (int n = 0; n < 4; ++n)
          acc[m][n] = __builtin_amdgcn_mfma_f32_16x16x32_bf16(fa2[m], fb2[n], acc[m][n], 0, 0, 0);
    }
    if (pf) {
      char* dA = ldsA[cur ^ 1];
      char* dB = ldsB[cur ^ 1];
#pragma unroll
      for (int i = 0; i < 8; ++i) {
        u32x2 d;
        d[0] = pack_bf2_rne(fa[i][0], fa[i][1]);
        d[1] = pack_bf2_rne(fa[i][2], fa[i][3]);
        *(u32x2*)(&dA[lo[i]]) = d;
      }
#pragma unroll
      for (int i = 0; i < 8; ++i) {
        u32x2 d;
        d[0] = pack_bf2_exact(fb[i][0] - ofv[i], fb[i][1] - ofv[i]);
        d[1] = pack_bf2_exact(fb[i][2] - ofv[i], fb[i][3] - ofv[i]);
        *(u32x2*)(&dB[lo[i]]) = d;
      }
    }
    __syncthreads();
  }

  const int col0 = bcol + fwc * 64 + (lane & 15);
  const int row0 = brow + fwr * 64 + ((lane >> 4) << 2);
#pragma unroll
  for (int n = 0; n < 4; ++n) {
    const int col = col0 + n * 16;
    const float s = Scale[col];
#pragma unroll
    for (int m = 0; m < 4; ++m) {
      const int r = row0 + m * 16;
#pragma unroll
      for (int j = 0; j < 4; ++j)
        Out[(long)(r + j) * DOUT + col] = acc[m][n][j] * s;
    }
  }
}

extern "C" void kernel_launch(void* const* d_in, const int* in_sizes, int n_in,
                              void* d_out, int out_size, void* d_ws, size_t ws_size,
                              hipStream_t stream) {
  (void)in_sizes; (void)n_in; (void)out_size;
  const float* X  = (const float*)d_in[0];
  const int*   W  = (const int*)d_in[1];
  const float* Sc = (const float*)d_in[2];
  const int*   Of = (const int*)d_in[3];
  float* Out = (float*)d_out;

  const size_t needA = (size_t)MTOT * DIN * 2;
  const size_t needB = (size_t)DOUT * DIN * 2;
  if (ws_size >= needA + needB) {
    u32x4* wsA = (u32x4*)d_ws;
    u32x4* wsB = (u32x4*)((char*)d_ws + needA);
    conv_kernel<<<3072, 256, 0, stream>>>(X, wsA, W, Of, wsB);
    gemm8_kernel<<<NWG, 512, 0, stream>>>(wsA, wsB, Sc, Out);
  } else {
    gemm_fused_kernel<<<2048, 256, 0, stream>>>(X, W, Of, Sc, Out);
  }
}

// Round 10
// 277.920 us; speedup vs baseline: 1.0107x; 1.0107x over previous
//
#include <hip/hip_runtime.h>
#include <stdint.h>

#define DIN   4096
#define DOUT  4096
#define MTOT  8192
#define NT    64                      /* K-tiles of BK=64 */

#define BM    256
#define BN    256
#define GRID_M (MTOT / BM)            /* 32 */
#define GRID_N (DOUT / BN)            /* 16 */
#define NWG   (GRID_M * GRID_N)       /* 512 */

typedef __attribute__((ext_vector_type(4)))  float        f32x4;
typedef __attribute__((ext_vector_type(16))) float        f32x16;
typedef __attribute__((ext_vector_type(4)))  int          i32x4;
typedef __attribute__((ext_vector_type(4)))  unsigned int u32x4;
typedef __attribute__((ext_vector_type(2)))  unsigned int u32x2;
typedef __attribute__((ext_vector_type(8)))  short        bf16x8;

__device__ __forceinline__ unsigned int pack_bf2_rne(float a, float b) {
  unsigned int ua = __builtin_bit_cast(unsigned int, a);
  unsigned int ub = __builtin_bit_cast(unsigned int, b);
  ua += 0x7fffu + ((ua >> 16) & 1u);
  ub += 0x7fffu + ((ub >> 16) & 1u);
  return (ua >> 16) | (ub & 0xffff0000u);
}

// (w - off) integer, |v| <= 135 < 256 -> exact in bf16.
__device__ __forceinline__ unsigned int pack_bf2_exact(int a, int b) {
  unsigned int ua = __builtin_bit_cast(unsigned int, (float)a);
  unsigned int ub = __builtin_bit_cast(unsigned int, (float)b);
  return (ua >> 16) | (ub & 0xffff0000u);
}

// ---- merged pre-pass: x->bf16 and (w-off)->bf16 into CHUNK-MAJOR 16KiB units ----
// unit = one (128-row group, k-tile) pair; within unit: byte = ch*2048 + row*16
// (ch = k-chunk 0..7 of 16B). Thread order row*8+ch: reads are 256B-contiguous
// per 8 threads; the single store instruction covers full 64B lines (4 rows/line
// written by 4 lanes of the same instruction).
#define UNITS_A (GRID_M * 2 * NT)     /* 4096 */
#define UNITS_B (GRID_N * 2 * NT)     /* 2048 — note: DOUT/128 * NT = 32*64 = 2048 */
__global__ __launch_bounds__(256) void conv_kernel(const float* __restrict__ X,
                                                   u32x4* __restrict__ wsA,
                                                   const int* __restrict__ W,
                                                   const int* __restrict__ Off,
                                                   u32x4* __restrict__ wsB) {
  const int totA = UNITS_A * 1024;
  const int totB = UNITS_B * 1024;
  for (int idx = blockIdx.x * 256 + threadIdx.x; idx < totA + totB;
       idx += gridDim.x * 256) {
    if (idx < totA) {
      const int pos = idx & 1023;
      const int row = pos >> 3, ch = pos & 7;
      const int unit = idx >> 10;
      const int kt = unit & (NT - 1), rb = unit >> 6;
      const int m = rb * 128 + row;
      const f32x4* src = (const f32x4*)(X + ((long)m << 12) + kt * 64 + ch * 8);
      f32x4 f0 = src[0], f1 = src[1];
      u32x4 d;
      d[0] = pack_bf2_rne(f0[0], f0[1]);
      d[1] = pack_bf2_rne(f0[2], f0[3]);
      d[2] = pack_bf2_rne(f1[0], f1[1]);
      d[3] = pack_bf2_rne(f1[2], f1[3]);
      wsA[(long)unit * 1024 + ch * 128 + row] = d;
    } else {
      const int j = idx - totA;
      const int pos = j & 1023;
      const int row = pos >> 3, ch = pos & 7;
      const int unit = j >> 10;
      const int kt = unit & (NT - 1), nb = unit >> 6;
      const int n = nb * 128 + row;
      const i32x4* src = (const i32x4*)(W + ((long)n << 12) + kt * 64 + ch * 8);
      const int off = Off[n];
      i32x4 w0 = src[0], w1 = src[1];
      u32x4 d;
      d[0] = pack_bf2_exact(w0[0] - off, w0[1] - off);
      d[1] = pack_bf2_exact(w0[2] - off, w0[3] - off);
      d[2] = pack_bf2_exact(w1[0] - off, w1[1] - off);
      d[3] = pack_bf2_exact(w1[2] - off, w1[3] - off);
      wsB[(long)unit * 1024 + ch * 128 + row] = d;
    }
  }
}

// ======= 32x32x16-MFMA 256x256 GEMM, chunk-major LDS, round-8 staging ledger =======
// Wave (8 = 2M x 4N) output 128x64 = 4 mt x 2 nt tiles of 32x32; acc f32x16 x8.
// A frag (mt,kk): lane l -> row mt*32+(l&31), k-chunk 2kk+(l>>5) (16B) — family
// pattern of the verified 16x16x32 layout. B symmetric (col = l&31).
// LDS unit [ch 0..7][row 0..127]*16B: a wave read = two contiguous 512B segs ->
// conflict-free. Phases per tile: ph0 {B all 8 + A(mt0) = 12 reads}, ph1..3
// {A(mt_i) 4 reads}; 8 MFMA/phase, LGKM(3..0) cascade, setprio, BAR per phase.
// Staging per tile t (buf=t&1): ph0:A0(t+1) ph1:A1(t+1) ph2:B0(t+2) ph3:B1(t+2).
// B of buf only read in ph0 -> ph2/3 staging into it is WAR-safe (post-ph0 BAR,
// round-8 argument). vmcnt ledger at ph3: B(t+1)4 + A(t+1)4 + B(t+2)4 = 12 ->
// WAITV(4) retires all of t+1 before tile-end BAR. Tail: WAITV(0) at t=62.

#define BAR()   __builtin_amdgcn_s_barrier()
#define SB()    __builtin_amdgcn_sched_barrier(0)
#define LGKM_(N) asm volatile("s_waitcnt lgkmcnt(" #N ")" ::: "memory")
#define LGKM(N)  LGKM_(N)
#define WAITV(N) asm volatile("s_waitcnt vmcnt(" #N ")" ::: "memory")

typedef __attribute__((address_space(3))) const char* ldsp;

#define DSR(dst, p, IMM) \
  asm volatile("ds_read_b128 %0, %1 offset:" #IMM : "=v"(dst) : "v"(p))

#define STAGE(ldsArr, bufc, h, basePtr, t)                                      \
  { const u32x4* s_ = (basePtr) + (long)(t) * 1024;                             \
    _Pragma("unroll")                                                           \
    for (int i_ = 0; i_ < 2; ++i_) {                                            \
      const int o_ = tid + i_ * 512;                                            \
      __builtin_amdgcn_global_load_lds(                                         \
          (const __attribute__((address_space(1))) void*)(s_ + o_),             \
          (__attribute__((address_space(3))) void*)(&ldsArr[bufc][h][0] + o_),  \
          16, 0, 0);                                                            \
    } }

// B frags kk-major: offset = kk*4096 + nt*512
#define RD_B8(pB_)                                                              \
  DSR(bR[0][0], pB_, 0);     DSR(bR[0][1], pB_, 512);                           \
  DSR(bR[1][0], pB_, 4096);  DSR(bR[1][1], pB_, 4608);                          \
  DSR(bR[2][0], pB_, 8192);  DSR(bR[2][1], pB_, 8704);                          \
  DSR(bR[3][0], pB_, 12288); DSR(bR[3][1], pB_, 12800);
// A frags for one mt: offset = kk*4096 + mt*512
#define RD_A4(pA_, O0, O1, O2, O3)                                              \
  DSR(aR[0], pA_, O0); DSR(aR[1], pA_, O1);                                     \
  DSR(aR[2], pA_, O2); DSR(aR[3], pA_, O3);

#define MMA2(kk, mt)                                                            \
  acc[mt][0] = __builtin_amdgcn_mfma_f32_32x32x16_bf16(aR[kk], bR[kk][0],       \
                                                       acc[mt][0], 0, 0, 0);    \
  acc[mt][1] = __builtin_amdgcn_mfma_f32_32x32x16_bf16(aR[kk], bR[kk][1],       \
                                                       acc[mt][1], 0, 0, 0);

#define CASC(mt)                                                                \
  __builtin_amdgcn_s_setprio(1);                                                \
  LGKM(3); SB(); MMA2(0, mt)                                                    \
  LGKM(2); SB(); MMA2(1, mt)                                                    \
  LGKM(1); SB(); MMA2(2, mt)                                                    \
  LGKM(0); SB(); MMA2(3, mt)                                                    \
  __builtin_amdgcn_s_setprio(0);

#define TILE(pA_, pB_, ABUF, BBUF, t, SA, SBf, WV)                              \
  RD_B8(pB_) RD_A4(pA_, 0, 4096, 8192, 12288)                                   \
  if (SA) { STAGE(ldsA, ABUF, 0, bA0, (t) + 1) }                                \
  CASC(0) BAR();                                                                \
  RD_A4(pA_, 512, 4608, 8704, 12800)                                            \
  if (SA) { STAGE(ldsA, ABUF, 1, bA1, (t) + 1) }                                \
  CASC(1) BAR();                                                                \
  RD_A4(pA_, 1024, 5120, 9216, 13312)                                           \
  if (SBf) { STAGE(ldsB, BBUF, 0, bB0, (t) + 2) }                               \
  CASC(2) BAR();                                                                \
  RD_A4(pA_, 1536, 5632, 9728, 13824)                                           \
  if (SBf) { STAGE(ldsB, BBUF, 1, bB1, (t) + 2) }                               \
  WV; CASC(3) BAR();

__global__ __launch_bounds__(512, 2) void gemm8_kernel(
    const u32x4* __restrict__ wsA, const u32x4* __restrict__ wsB,
    const float* __restrict__ Scale, float* __restrict__ Out) {
  __shared__ u32x4 ldsA[2][2][1024];   // [buf][unit][ch*128+row] = 64 KiB
  __shared__ u32x4 ldsB[2][2][1024];

  const int tid  = threadIdx.x;
  const int lane = tid & 63;
  const int wid  = tid >> 6;
  const int wr   = wid >> 2;     // A unit (128-row half)
  const int wc   = wid & 3;      // 64-col N slice
  const int wch  = wc >> 1;      // B unit
  const int lane31 = lane & 31;
  const int lhi    = lane >> 5;

  int gid = (int)blockIdx.x;
  gid = (gid & 7) * (NWG >> 3) + (gid >> 3);   // bijective XCD swizzle (512%8==0)
  const int wg_m = gid / GRID_N;
  const int wg_n = gid % GRID_N;

  // lane byte offsets into a unit: row part + k-chunk-parity part
  const int lanepA = lane31 * 16 + lhi * 2048;
  const int lanepB = (wc & 1) * 1024 + lane31 * 16 + lhi * 2048;

  ldsp pA0 = (ldsp)((const char*)&ldsA[0][wr][0] + lanepA);
  ldsp pA1 = (ldsp)((const char*)&ldsA[1][wr][0] + lanepA);
  ldsp pB0 = (ldsp)((const char*)&ldsB[0][wch][0] + lanepB);
  ldsp pB1 = (ldsp)((const char*)&ldsB[1][wch][0] + lanepB);

  const u32x4* bA0 = wsA + (long)(wg_m * 2 + 0) * NT * 1024;
  const u32x4* bA1 = wsA + (long)(wg_m * 2 + 1) * NT * 1024;
  const u32x4* bB0 = wsB + (long)(wg_n * 2 + 0) * NT * 1024;
  const u32x4* bB1 = wsB + (long)(wg_n * 2 + 1) * NT * 1024;

  f32x16 acc[4][2];
#pragma unroll
  for (int m = 0; m < 4; ++m)
#pragma unroll
    for (int n = 0; n < 2; ++n)
#pragma unroll
      for (int q = 0; q < 16; ++q) acc[m][n][q] = 0.f;

  bf16x8 aR[4], bR[4][2];

  // prologue: tile0 all 4 units + tile1 B units; retire tile0 (vmcnt(4))
  STAGE(ldsB, 0, 0, bB0, 0) STAGE(ldsA, 0, 0, bA0, 0)
  STAGE(ldsB, 0, 1, bB1, 0) STAGE(ldsA, 0, 1, bA1, 0)
  STAGE(ldsB, 1, 0, bB0, 1) STAGE(ldsB, 1, 1, bB1, 1)
  WAITV(4); BAR();

#pragma unroll 1
  for (int it = 0; it < 31; ++it) {            // tiles 0..61
    const int t = 2 * it;
    TILE(pA0, pB0, 1, 0, t,     1, 1, WAITV(4))
    TILE(pA1, pB1, 0, 1, t + 1, 1, 1, WAITV(4))
  }
  TILE(pA0, pB0, 1, 0, 62, 1, 0, WAITV(0))     // stage A(63), drain
  TILE(pA1, pB1, 0, 1, 63, 0, 0, )             // compute only

  // epilogue: out = acc * scale[col]
  // 32x32 C/D map (m74/m101): col = lane&31, row = (reg&3)+8*(reg>>2)+4*(lane>>5)
  const int col0 = wg_n * BN + wc * 64 + lane31;
  const int row0 = wg_m * BM + wr * 128 + lhi * 4;
#pragma unroll
  for (int nt = 0; nt < 2; ++nt) {
    const int col = col0 + nt * 32;
    const float s = Scale[col];
#pragma unroll
    for (int mt = 0; mt < 4; ++mt) {
      const int rb = row0 + mt * 32;
#pragma unroll
      for (int q = 0; q < 4; ++q)
#pragma unroll
        for (int j = 0; j < 4; ++j)
          Out[(long)(rb + q * 8 + j) * DOUT + col] = acc[mt][nt][q * 4 + j] * s;
    }
  }
}

// ================= fallback: fused 128x128 (round-1, proven) =================
__global__ __launch_bounds__(256, 2) void gemm_fused_kernel(
    const float* __restrict__ X, const int* __restrict__ W,
    const int* __restrict__ Off, const float* __restrict__ Scale,
    float* __restrict__ Out) {
  __shared__ char ldsA[2][128 * 64 * 2];
  __shared__ char ldsB[2][128 * 64 * 2];

  const int tid  = threadIdx.x;
  const int lane = tid & 63;
  const int wid  = tid >> 6;
  const int fwr  = wid >> 1;
  const int fwc  = wid & 1;

  int gid = (int)blockIdx.x;
  gid = (gid & 7) * (2048 >> 3) + (gid >> 3);
  const int wg_m = gid / 32;
  const int wg_n = gid % 32;
  const int brow = wg_m * 128;
  const int bcol = wg_n * 128;

  f32x4 acc[4][4];
#pragma unroll
  for (int m = 0; m < 4; ++m)
#pragma unroll
    for (int n = 0; n < 4; ++n) acc[m][n] = (f32x4){0.f, 0.f, 0.f, 0.f};

  int aoff[2][4], boff[2][4];
#pragma unroll
  for (int kk = 0; kk < 2; ++kk)
#pragma unroll
    for (int m = 0; m < 4; ++m) {
      const int kb = kk * 64 + ((lane >> 4) << 4);
      const int ra = fwr * 64 + m * 16 + (lane & 15);
      const int rb = fwc * 64 + m * 16 + (lane & 15);
      aoff[kk][m] = ra * 128 + (kb ^ ((ra & 7) << 4));
      boff[kk][m] = rb * 128 + (kb ^ ((rb & 7) << 4));
    }

  long xo[8], wo[8];
  int lo[8], ofv[8];
#pragma unroll
  for (int i = 0; i < 8; ++i) {
    const int idx = tid + i * 256;
    const int row = idx >> 4, c4 = idx & 15;
    xo[i] = (long)(brow + row) * DIN + c4 * 4;
    wo[i] = (long)(bcol + row) * DIN + c4 * 4;
    lo[i] = row * 128 + ((c4 * 8) ^ ((row & 7) << 4));
    ofv[i] = Off[bcol + row];
  }
  {
#pragma unroll
    for (int i = 0; i < 8; ++i) {
      f32x4 f = *(const f32x4*)(X + xo[i]);
      u32x2 d;
      d[0] = pack_bf2_rne(f[0], f[1]);
      d[1] = pack_bf2_rne(f[2], f[3]);
      *(u32x2*)(&ldsA[0][lo[i]]) = d;
    }
#pragma unroll
    for (int i = 0; i < 8; ++i) {
      i32x4 w = *(const i32x4*)(W + wo[i]);
      u32x2 d;
      d[0] = pack_bf2_exact(w[0] - ofv[i], w[1] - ofv[i]);
      d[1] = pack_bf2_exact(w[2] - ofv[i], w[3] - ofv[i]);
      *(u32x2*)(&ldsB[0][lo[i]]) = d;
    }
  }
  __syncthreads();
#pragma unroll 1
  for (int kt = 0; kt < NT; ++kt) {
    const int cur = kt & 1;
    const bool pf = (kt + 1 < NT);
    f32x4 fa[8];
    i32x4 fb[8];
    if (pf) {
      const int ko = (kt + 1) * 64;
#pragma unroll
      for (int i = 0; i < 8; ++i) fa[i] = *(const f32x4*)(X + xo[i] + ko);
#pragma unroll
      for (int i = 0; i < 8; ++i) fb[i] = *(const i32x4*)(W + wo[i] + ko);
    }
#pragma unroll
    for (int kk = 0; kk < 2; ++kk) {
      bf16x8 fa2[4], fb2[4];
#pragma unroll
      for (int m = 0; m < 4; ++m)
        fa2[m] = __builtin_bit_cast(bf16x8, *(const u32x4*)(&ldsA[cur][aoff[kk][m]]));
#pragma unroll
      for (int n = 0; n < 4; ++n)
        fb2[n] = __builtin_bit_cast(bf16x8, *(const u32x4*)(&ldsB[cur][boff[kk][n]]));
#pragma unroll
      for (int m = 0; m < 4; ++m)
#pragma unroll
        for (int n = 0; n < 4; ++n)
          acc[m][n] = __builtin_amdgcn_mfma_f32_16x16x32_bf16(fa2[m], fb2[n], acc[m][n], 0, 0, 0);
    }
    if (pf) {
      char* dA = ldsA[cur ^ 1];
      char* dB = ldsB[cur ^ 1];
#pragma unroll
      for (int i = 0; i < 8; ++i) {
        u32x2 d;
        d[0] = pack_bf2_rne(fa[i][0], fa[i][1]);
        d[1] = pack_bf2_rne(fa[i][2], fa[i][3]);
        *(u32x2*)(&dA[lo[i]]) = d;
      }
#pragma unroll
      for (int i = 0; i < 8; ++i) {
        u32x2 d;
        d[0] = pack_bf2_exact(fb[i][0] - ofv[i], fb[i][1] - ofv[i]);
        d[1] = pack_bf2_exact(fb[i][2] - ofv[i], fb[i][3] - ofv[i]);
        *(u32x2*)(&dB[lo[i]]) = d;
      }
    }
    __syncthreads();
  }

  const int col0 = bcol + fwc * 64 + (lane & 15);
  const int row0 = brow + fwr * 64 + ((lane >> 4) << 2);
#pragma unroll
  for (int n = 0; n < 4; ++n) {
    const int col = col0 + n * 16;
    const float s = Scale[col];
#pragma unroll
    for (int m = 0; m < 4; ++m) {
      const int r = row0 + m * 16;
#pragma unroll
      for (int j = 0; j < 4; ++j)
        Out[(long)(r + j) * DOUT + col] = acc[m][n][j] * s;
    }
  }
}

extern "C" void kernel_launch(void* const* d_in, const int* in_sizes, int n_in,
                              void* d_out, int out_size, void* d_ws, size_t ws_size,
                              hipStream_t stream) {
  (void)in_sizes; (void)n_in; (void)out_size;
  const float* X  = (const float*)d_in[0];
  const int*   W  = (const int*)d_in[1];
  const float* Sc = (const float*)d_in[2];
  const int*   Of = (const int*)d_in[3];
  float* Out = (float*)d_out;

  const size_t needA = (size_t)MTOT * DIN * 2;
  const size_t needB = (size_t)DOUT * DIN * 2;
  if (ws_size >= needA + needB) {
    u32x4* wsA = (u32x4*)d_ws;
    u32x4* wsB = (u32x4*)((char*)d_ws + needA);
    conv_kernel<<<3072, 256, 0, stream>>>(X, wsA, W, Of, wsB);
    gemm8_kernel<<<NWG, 512, 0, stream>>>(wsA, wsB, Sc, Out);
  } else {
    gemm_fused_kernel<<<2048, 256, 0, stream>>>(X, W, Of, Sc, Out);
  }
}